// Round 1
// baseline (4518.867 us; speedup 1.0000x reference)
//
#include <hip/hip_runtime.h>
#include <cstdint>
#include <cstddef>

#define BATCH 4
#define CCH   256
#define HW    4096   // H*W; also N == M == 4096
#define NM    4096

// ---------------------------------------------------------------------------
// k_E: E[b,d,n] = sum_c We[d,c] * X[b,c,n]      (X = input_1 reshaped (c,n))
// grid (16 n-tiles, 64 d-tiles, B), block 256
// ---------------------------------------------------------------------------
__global__ __launch_bounds__(256) void k_E(const float* __restrict__ in1,
                                           const float* __restrict__ We,
                                           float* __restrict__ E) {
    int t  = threadIdx.x;
    int n  = blockIdx.x * 256 + t;
    int d0 = blockIdx.y * 4;
    int b  = blockIdx.z;
    const float* X = in1 + (size_t)b * CCH * HW;
    float a0 = 0.f, a1 = 0.f, a2 = 0.f, a3 = 0.f;
    for (int c = 0; c < CCH; ++c) {
        float x = X[(size_t)c * HW + n];
        a0 = fmaf(x, We[(d0 + 0) * CCH + c], a0);
        a1 = fmaf(x, We[(d0 + 1) * CCH + c], a1);
        a2 = fmaf(x, We[(d0 + 2) * CCH + c], a2);
        a3 = fmaf(x, We[(d0 + 3) * CCH + c], a3);
    }
    float* Eb = E + (size_t)b * CCH * HW;
    Eb[(size_t)(d0 + 0) * HW + n] = a0;
    Eb[(size_t)(d0 + 1) * HW + n] = a1;
    Eb[(size_t)(d0 + 2) * HW + n] = a2;
    Eb[(size_t)(d0 + 3) * HW + n] = a3;
}

// ---------------------------------------------------------------------------
// k_A: A[z,n,m] = sum_d E[b,d,n] * Q[b,d,m]   (Q = input_2 reshaped (c,m))
// 64x64 tile, BK=16, 256 threads, 4x4 acc/thread. grid (64,64,g)
// ---------------------------------------------------------------------------
__global__ __launch_bounds__(256) void k_A(const float* __restrict__ E,
                                           const float* __restrict__ in2,
                                           float* __restrict__ A, int bbase) {
    __shared__ float Es[16][68];
    __shared__ float Qs[16][68];
    int t  = threadIdx.x;
    int m0 = blockIdx.x * 64;
    int n0 = blockIdx.y * 64;
    int z  = blockIdx.z;
    int b  = bbase + z;
    const float* Eb = E   + (size_t)b * CCH * HW;
    const float* Qb = in2 + (size_t)b * CCH * HW;
    int lm = t % 64;      // load column
    int li = t / 64;      // load row base (0..3)
    int tx = t % 16, ty = t / 16;
    float acc[4][4] = {};
    for (int k0 = 0; k0 < CCH; k0 += 16) {
#pragma unroll
        for (int r = 0; r < 4; ++r) {
            int i = li + r * 4;
            Es[i][lm] = Eb[(size_t)(k0 + i) * HW + n0 + lm];
            Qs[i][lm] = Qb[(size_t)(k0 + i) * HW + m0 + lm];
        }
        __syncthreads();
#pragma unroll
        for (int kk = 0; kk < 16; ++kk) {
            float4 av = *(const float4*)&Es[kk][ty * 4];
            float4 bv = *(const float4*)&Qs[kk][tx * 4];
            float a_[4] = {av.x, av.y, av.z, av.w};
            float b_[4] = {bv.x, bv.y, bv.z, bv.w};
#pragma unroll
            for (int i = 0; i < 4; ++i)
#pragma unroll
                for (int j = 0; j < 4; ++j)
                    acc[i][j] = fmaf(a_[i], b_[j], acc[i][j]);
        }
        __syncthreads();
    }
    float* Az = A + (size_t)z * NM * NM;
#pragma unroll
    for (int i = 0; i < 4; ++i) {
        float4 v = make_float4(acc[i][0], acc[i][1], acc[i][2], acc[i][3]);
        *(float4*)&Az[(size_t)(n0 + ty * 4 + i) * NM + m0 + tx * 4] = v;
    }
}

// ---------------------------------------------------------------------------
// k_rowsum: rowsum[b,n] = sum_m exp(A[z,n,m]).  grid (4096, g), block 256
// ---------------------------------------------------------------------------
__global__ __launch_bounds__(256) void k_rowsum(const float* __restrict__ A,
                                                float* __restrict__ rowsum, int bbase) {
    int t = threadIdx.x;
    int n = blockIdx.x;
    int z = blockIdx.y;
    const float* row = A + ((size_t)z * NM + n) * NM;
    float s = 0.f;
#pragma unroll
    for (int k = 0; k < 16; ++k) s += __expf(row[t + k * 256]);
#pragma unroll
    for (int off = 32; off > 0; off >>= 1) s += __shfl_down(s, off, 64);
    __shared__ float red[4];
    int lane = t & 63, wid = t >> 6;
    if (lane == 0) red[wid] = s;
    __syncthreads();
    if (t == 0) rowsum[(size_t)(bbase + z) * NM + n] = red[0] + red[1] + red[2] + red[3];
}

// ---------------------------------------------------------------------------
// k_colpart / k_colsum: colsum[b,m] = sum_n exp(A[z,n,m]), split over 16 n-segs
// ---------------------------------------------------------------------------
__global__ __launch_bounds__(256) void k_colpart(const float* __restrict__ A,
                                                 float* __restrict__ pcol, int bbase) {
    int t  = threadIdx.x;
    int m  = blockIdx.x * 256 + t;
    int ns = blockIdx.y;
    int z  = blockIdx.z;
    const float* Az = A + (size_t)z * NM * NM;
    float s = 0.f;
    int nbeg = ns * 256;
    for (int n = nbeg; n < nbeg + 256; ++n) s += __expf(Az[(size_t)n * NM + m]);
    pcol[((size_t)(bbase + z) * 16 + ns) * NM + m] = s;
}

__global__ __launch_bounds__(256) void k_colsum(const float* __restrict__ pcol,
                                                float* __restrict__ colsum, int bbase) {
    int t = threadIdx.x;
    int m = blockIdx.x * 256 + t;
    int b = bbase + blockIdx.y;
    float s = 0.f;
#pragma unroll
    for (int ns = 0; ns < 16; ++ns) s += pcol[((size_t)b * 16 + ns) * NM + m];
    colsum[(size_t)b * NM + m] = s;
}

// ---------------------------------------------------------------------------
// k_qatt: qatt[b,c,m] = (sum_n X[b,c,n]*exp(A[z,n,m])) / colsum[b,m]
// 128(c) x 64(m) tile, BK=16 over n. grid (64, 2, g), block 256, 8x4 acc.
// ---------------------------------------------------------------------------
__global__ __launch_bounds__(256) void k_qatt(const float* __restrict__ in1,
                                              const float* __restrict__ A,
                                              const float* __restrict__ colsum,
                                              float* __restrict__ qatt, int bbase) {
    __shared__ float Xs[16][136];
    __shared__ float Es[16][68];
    int t  = threadIdx.x;
    int m0 = blockIdx.x * 64;
    int c0 = blockIdx.y * 128;
    int z  = blockIdx.z;
    int b  = bbase + z;
    const float* X  = in1 + (size_t)b * CCH * HW;
    const float* Az = A + (size_t)z * NM * NM;
    int xi = t % 16, xj0 = t / 16;   // X load: k-offset xi, c-offset xj0+16r
    int am = t % 64, ai0 = t / 64;   // A load: m-offset am, k-row ai0+4r
    int tx = t % 16, ty = t / 16;
    float acc[8][4] = {};
    for (int k0 = 0; k0 < NM; k0 += 16) {
#pragma unroll
        for (int r = 0; r < 8; ++r) {
            int c = xj0 + r * 16;
            Xs[xi][c] = X[(size_t)(c0 + c) * HW + k0 + xi];
        }
#pragma unroll
        for (int r = 0; r < 4; ++r) {
            int i = ai0 + r * 4;
            Es[i][am] = __expf(Az[(size_t)(k0 + i) * NM + m0 + am]);
        }
        __syncthreads();
#pragma unroll
        for (int kk = 0; kk < 16; ++kk) {
            float4 a0 = *(const float4*)&Xs[kk][ty * 8];
            float4 a1 = *(const float4*)&Xs[kk][ty * 8 + 4];
            float4 bv = *(const float4*)&Es[kk][tx * 4];
            float a_[8] = {a0.x, a0.y, a0.z, a0.w, a1.x, a1.y, a1.z, a1.w};
            float b_[4] = {bv.x, bv.y, bv.z, bv.w};
#pragma unroll
            for (int i = 0; i < 8; ++i)
#pragma unroll
                for (int j = 0; j < 4; ++j)
                    acc[i][j] = fmaf(a_[i], b_[j], acc[i][j]);
        }
        __syncthreads();
    }
    float cs[4];
#pragma unroll
    for (int j = 0; j < 4; ++j) cs[j] = colsum[(size_t)b * NM + m0 + tx * 4 + j];
    float* Qa = qatt + (size_t)b * CCH * HW;
#pragma unroll
    for (int i = 0; i < 8; ++i) {
        float4 v = make_float4(acc[i][0] / cs[0], acc[i][1] / cs[1],
                               acc[i][2] / cs[2], acc[i][3] / cs[3]);
        *(float4*)&Qa[(size_t)(c0 + ty * 8 + i) * HW + m0 + tx * 4] = v;
    }
}

// ---------------------------------------------------------------------------
// k_eatt: eatt[b,c,n] = (sum_m Q[b,c,m]*exp(A[z,n,m])) / rowsum[b,n]
// 128(c) x 64(n) tile, BK=16 over m. grid (64, 2, g), block 256.
// ---------------------------------------------------------------------------
__global__ __launch_bounds__(256) void k_eatt(const float* __restrict__ in2,
                                              const float* __restrict__ A,
                                              const float* __restrict__ rowsum,
                                              float* __restrict__ eatt, int bbase) {
    __shared__ float Qs[16][136];
    __shared__ float Ps[16][68];
    int t  = threadIdx.x;
    int n0 = blockIdx.x * 64;
    int c0 = blockIdx.y * 128;
    int z  = blockIdx.z;
    int b  = bbase + z;
    const float* Q  = in2 + (size_t)b * CCH * HW;
    const float* Az = A + (size_t)z * NM * NM;
    int xi = t % 16, xj0 = t / 16;   // Q load
    int pi = t % 16, pj0 = t / 16;   // A load: m-offset pi, n-offset pj0+16r
    int tx = t % 16, ty = t / 16;
    float acc[8][4] = {};
    for (int k0 = 0; k0 < NM; k0 += 16) {
#pragma unroll
        for (int r = 0; r < 8; ++r) {
            int c = xj0 + r * 16;
            Qs[xi][c] = Q[(size_t)(c0 + c) * HW + k0 + xi];
        }
#pragma unroll
        for (int r = 0; r < 4; ++r) {
            int j = pj0 + r * 16;
            Ps[pi][j] = __expf(Az[(size_t)(n0 + j) * NM + k0 + pi]);
        }
        __syncthreads();
#pragma unroll
        for (int kk = 0; kk < 16; ++kk) {
            float4 a0 = *(const float4*)&Qs[kk][ty * 8];
            float4 a1 = *(const float4*)&Qs[kk][ty * 8 + 4];
            float4 bv = *(const float4*)&Ps[kk][tx * 4];
            float a_[8] = {a0.x, a0.y, a0.z, a0.w, a1.x, a1.y, a1.z, a1.w};
            float b_[4] = {bv.x, bv.y, bv.z, bv.w};
#pragma unroll
            for (int i = 0; i < 8; ++i)
#pragma unroll
                for (int j = 0; j < 4; ++j)
                    acc[i][j] = fmaf(a_[i], b_[j], acc[i][j]);
        }
        __syncthreads();
    }
    float rs[4];
#pragma unroll
    for (int j = 0; j < 4; ++j) rs[j] = rowsum[(size_t)b * NM + n0 + tx * 4 + j];
    float* Ea = eatt + (size_t)b * CCH * HW;
#pragma unroll
    for (int i = 0; i < 8; ++i) {
        float4 v = make_float4(acc[i][0] / rs[0], acc[i][1] / rs[1],
                               acc[i][2] / rs[2], acc[i][3] / rs[3]);
        *(float4*)&Ea[(size_t)(c0 + ty * 8 + i) * HW + n0 + tx * 4] = v;
    }
}

// ---------------------------------------------------------------------------
// k_gate: m1[b,p] = sigmoid(sum_c eatt[b,c,p]*gw[c]);  m2 likewise from qatt.
// grid (16, B, 2), block 256
// ---------------------------------------------------------------------------
__global__ __launch_bounds__(256) void k_gate(const float* __restrict__ eatt,
                                              const float* __restrict__ qatt,
                                              const float* __restrict__ gw,
                                              float* __restrict__ m1,
                                              float* __restrict__ m2) {
    int t = threadIdx.x;
    int p = blockIdx.x * 256 + t;
    int b = blockIdx.y;
    int which = blockIdx.z;
    const float* att = (which == 0 ? eatt : qatt) + (size_t)b * CCH * HW;
    float s = 0.f;
    for (int c = 0; c < CCH; ++c) s = fmaf(att[(size_t)c * HW + p], gw[c], s);
    float sg = 1.f / (1.f + __expf(-s));
    (which == 0 ? m1 : m2)[(size_t)b * HW + p] = sg;
}

// ---------------------------------------------------------------------------
// k_final: out[b,o,p] = m[b,p]*sum_c att[b,c,p]*Wf[o,c] + sum_c inp[b,c,p]*Wf[o,256+c]
// 64(o) x 64(p) tile, two K=256 phases. grid (64, 4, B), block 256.
// ---------------------------------------------------------------------------
__global__ __launch_bounds__(256) void k_final(const float* __restrict__ att,
                                               const float* __restrict__ inp,
                                               const float* __restrict__ Wf,
                                               const float* __restrict__ mgate,
                                               float* __restrict__ outp) {
    __shared__ float Ws[16][68];
    __shared__ float Ts[16][68];
    int t  = threadIdx.x;
    int p0 = blockIdx.x * 64;
    int o0 = blockIdx.y * 64;
    int b  = blockIdx.z;
    const float* attb = att + (size_t)b * CCH * HW;
    const float* inb  = inp + (size_t)b * CCH * HW;
    int wi = t % 16, wj0 = t / 16;
    int tm = t % 64, ti0 = t / 64;
    int tx = t % 16, ty = t / 16;
    float accA[4][4] = {}, accB[4][4] = {};
    // phase 1: attention half (k = 0..255 of W rows)
    for (int k0 = 0; k0 < CCH; k0 += 16) {
#pragma unroll
        for (int r = 0; r < 4; ++r) {
            int j = wj0 + r * 16;
            Ws[wi][j] = Wf[(size_t)(o0 + j) * (2 * CCH) + k0 + wi];
        }
#pragma unroll
        for (int r = 0; r < 4; ++r) {
            int i = ti0 + r * 4;
            Ts[i][tm] = attb[(size_t)(k0 + i) * HW + p0 + tm];
        }
        __syncthreads();
#pragma unroll
        for (int kk = 0; kk < 16; ++kk) {
            float4 av = *(const float4*)&Ws[kk][ty * 4];
            float4 bv = *(const float4*)&Ts[kk][tx * 4];
            float a_[4] = {av.x, av.y, av.z, av.w};
            float b_[4] = {bv.x, bv.y, bv.z, bv.w};
#pragma unroll
            for (int i = 0; i < 4; ++i)
#pragma unroll
                for (int j = 0; j < 4; ++j)
                    accA[i][j] = fmaf(a_[i], b_[j], accA[i][j]);
        }
        __syncthreads();
    }
    // phase 2: input half (k = 256..511 of W rows)
    for (int k0 = 0; k0 < CCH; k0 += 16) {
#pragma unroll
        for (int r = 0; r < 4; ++r) {
            int j = wj0 + r * 16;
            Ws[wi][j] = Wf[(size_t)(o0 + j) * (2 * CCH) + CCH + k0 + wi];
        }
#pragma unroll
        for (int r = 0; r < 4; ++r) {
            int i = ti0 + r * 4;
            Ts[i][tm] = inb[(size_t)(k0 + i) * HW + p0 + tm];
        }
        __syncthreads();
#pragma unroll
        for (int kk = 0; kk < 16; ++kk) {
            float4 av = *(const float4*)&Ws[kk][ty * 4];
            float4 bv = *(const float4*)&Ts[kk][tx * 4];
            float a_[4] = {av.x, av.y, av.z, av.w};
            float b_[4] = {bv.x, bv.y, bv.z, bv.w};
#pragma unroll
            for (int i = 0; i < 4; ++i)
#pragma unroll
                for (int j = 0; j < 4; ++j)
                    accB[i][j] = fmaf(a_[i], b_[j], accB[i][j]);
        }
        __syncthreads();
    }
    float mv[4];
#pragma unroll
    for (int j = 0; j < 4; ++j) mv[j] = mgate[(size_t)b * HW + p0 + tx * 4 + j];
#pragma unroll
    for (int i = 0; i < 4; ++i) {
        float4 v = make_float4(accA[i][0] * mv[0] + accB[i][0],
                               accA[i][1] * mv[1] + accB[i][1],
                               accA[i][2] * mv[2] + accB[i][2],
                               accA[i][3] * mv[3] + accB[i][3]);
        *(float4*)&outp[((size_t)b * CCH + o0 + ty * 4 + i) * HW + p0 + tx * 4] = v;
    }
}

// ---------------------------------------------------------------------------
extern "C" void kernel_launch(void* const* d_in, const int* in_sizes, int n_in,
                              void* d_out, int out_size, void* d_ws, size_t ws_size,
                              hipStream_t stream) {
    const float* in1 = (const float*)d_in[0];
    const float* in2 = (const float*)d_in[1];
    const float* We  = (const float*)d_in[2];
    const float* gw  = (const float*)d_in[3];
    const float* W1  = (const float*)d_in[4];
    const float* W2  = (const float*)d_in[5];
    float* out = (float*)d_out;
    float* ws  = (float*)d_ws;

    const size_t Asz1 = (size_t)NM * NM;            // per-batch A (floats)
    const size_t ATT  = (size_t)BATCH * CCH * HW;   // 4,194,304 floats

    // bytes needed with all 4 batches of A resident
    size_t need4 = (4 * Asz1 + 3 * ATT + (size_t)BATCH * 16 * NM + 4 * (size_t)BATCH * NM)
                   * sizeof(float);
    int g = (ws_size >= need4) ? 4 : 1;   // deterministic per-session, graph-safe

    size_t off = 0;
    float* A      = ws + off; off += (size_t)g * Asz1;
    float* E      = ws + off; off += ATT;
    float* eatt   = ws + off; off += ATT;
    float* qatt   = ws + off; off += ATT;
    float* pcol   = ws + off; off += (size_t)BATCH * 16 * NM;
    float* rowsum = ws + off; off += (size_t)BATCH * NM;
    float* colsum = ws + off; off += (size_t)BATCH * NM;
    float* m1v    = ws + off; off += (size_t)BATCH * NM;
    float* m2v    = ws + off; off += (size_t)BATCH * NM;

    k_E<<<dim3(16, 64, BATCH), 256, 0, stream>>>(in1, We, E);

    for (int bbase = 0; bbase < BATCH; bbase += g) {
        k_A      <<<dim3(64, 64, g), 256, 0, stream>>>(E, in2, A, bbase);
        k_rowsum <<<dim3(NM,  g),    256, 0, stream>>>(A, rowsum, bbase);
        k_colpart<<<dim3(16, 16, g), 256, 0, stream>>>(A, pcol, bbase);
        k_colsum <<<dim3(16,  g),    256, 0, stream>>>(pcol, colsum, bbase);
        k_qatt   <<<dim3(64, 2, g),  256, 0, stream>>>(in1, A, colsum, qatt, bbase);
        k_eatt   <<<dim3(64, 2, g),  256, 0, stream>>>(in2, A, rowsum, eatt, bbase);
    }

    k_gate <<<dim3(16, BATCH, 2), 256, 0, stream>>>(eatt, qatt, gw, m1v, m2v);
    k_final<<<dim3(64, 4, BATCH), 256, 0, stream>>>(eatt, in1, W1, m1v, out);
    k_final<<<dim3(64, 4, BATCH), 256, 0, stream>>>(qatt, in2, W2, m2v,
                                                    out + (size_t)BATCH * CCH * HW);
}

// Round 2
// 686.973 us; speedup vs baseline: 6.5779x; 6.5779x over previous
//
#include <hip/hip_runtime.h>
#include <cstdint>
#include <cstddef>

#define BATCH 4
#define CCH   256
#define HW    4096
#define NM    4096

typedef __attribute__((ext_vector_type(8))) short s16x8;
typedef __attribute__((ext_vector_type(4))) float f32x4;

__device__ __forceinline__ short f2bf(float f) {
    unsigned u = __float_as_uint(f);
    u += 0x7FFFu + ((u >> 16) & 1u);
    return (short)(u >> 16);
}
__device__ __forceinline__ float bf2f(short s) {
    return __uint_as_float(((unsigned)(unsigned short)s) << 16);
}

// ---------------------------------------------------------------------------
// k_cast: fp32 -> bf16, same layout. n multiple of 4.
// ---------------------------------------------------------------------------
__global__ __launch_bounds__(256) void k_cast(const float* __restrict__ s,
                                              short* __restrict__ d, int n) {
    int i = (blockIdx.x * 256 + threadIdx.x) * 4;
    if (i + 3 < n) {
        float4 v = *(const float4*)&s[i];
        *(short4*)&d[i] = make_short4(f2bf(v.x), f2bf(v.y), f2bf(v.z), f2bf(v.w));
    }
}

// ---------------------------------------------------------------------------
// k_cast_tr: (b,c,p) fp32 -> (b,p,c) bf16.  grid (HW/64, CCH/64, B), block 256
// ---------------------------------------------------------------------------
__global__ __launch_bounds__(256) void k_cast_tr(const float* __restrict__ src,
                                                 short* __restrict__ dst) {
    __shared__ short S[64][72];
    int t = threadIdx.x;
    int p0 = blockIdx.x * 64, c0 = blockIdx.y * 64, b = blockIdx.z;
    const float* sb = src + (size_t)b * CCH * HW;
    short* db = dst + (size_t)b * HW * CCH;
    int tx = t & 15, ty = t >> 4;
#pragma unroll
    for (int i = 0; i < 4; ++i) {
        int c = ty + i * 16;
        float4 v = *(const float4*)&sb[(size_t)(c0 + c) * HW + p0 + tx * 4];
        S[tx * 4 + 0][c] = f2bf(v.x);
        S[tx * 4 + 1][c] = f2bf(v.y);
        S[tx * 4 + 2][c] = f2bf(v.z);
        S[tx * 4 + 3][c] = f2bf(v.w);
    }
    __syncthreads();
#pragma unroll
    for (int i = 0; i < 4; ++i) {
        int p = ty + i * 16;
        short4 v = *(const short4*)&S[p][tx * 4];
        *(short4*)&db[(size_t)(p0 + p) * CCH + c0 + tx * 4] = v;
    }
}

// ---------------------------------------------------------------------------
// k_E: E16n[b,n,d] = bf16( sum_c We[d,c] * in1[b,c,n] ).  grid (16,64,B)
// ---------------------------------------------------------------------------
__global__ __launch_bounds__(256) void k_E(const float* __restrict__ in1,
                                           const float* __restrict__ We,
                                           short* __restrict__ E16n) {
    int t = threadIdx.x;
    int n = blockIdx.x * 256 + t;
    int d0 = blockIdx.y * 4;
    int b = blockIdx.z;
    const float* X = in1 + (size_t)b * CCH * HW;
    float a0 = 0.f, a1 = 0.f, a2 = 0.f, a3 = 0.f;
    for (int c = 0; c < CCH; ++c) {
        float x = X[(size_t)c * HW + n];
        a0 = fmaf(x, We[(d0 + 0) * CCH + c], a0);
        a1 = fmaf(x, We[(d0 + 1) * CCH + c], a1);
        a2 = fmaf(x, We[(d0 + 2) * CCH + c], a2);
        a3 = fmaf(x, We[(d0 + 3) * CCH + c], a3);
    }
    short* Eb = E16n + (size_t)b * HW * CCH;
    *(short4*)&Eb[(size_t)n * CCH + d0] =
        make_short4(f2bf(a0), f2bf(a1), f2bf(a2), f2bf(a3));
}

// ---------------------------------------------------------------------------
// k_gemm_exp: Out[z][row,col] = bf16(exp( sum_d Aop[b,row,d]*Bop[b,col,d] ))
// Aop/Bop: (b, 4096, 256) bf16.  TM=TN=128, BK=32. grid (32,32,g), block 256.
// Call (E16n, Qt16)->P  and  (Qt16, E16n)->PT.
// ---------------------------------------------------------------------------
__global__ __launch_bounds__(256) void k_gemm_exp(const short* __restrict__ Aop,
                                                  const short* __restrict__ Bop,
                                                  short* __restrict__ Out,
                                                  int bbase) {
    __shared__ short As[128 * 40];
    __shared__ short Bs[128 * 40];
    int t = threadIdx.x;
    int col0 = blockIdx.x * 128, row0 = blockIdx.y * 128, z = blockIdx.z;
    const short* Ab = Aop + (size_t)(bbase + z) * HW * CCH;
    const short* Bb = Bop + (size_t)(bbase + z) * HW * CCH;
    short* Ob = Out + (size_t)z * NM * NM;
    int lm = t & 15, q = (t >> 4) & 3, w = t >> 6;
    int wr = (w >> 1) * 64, wc = (w & 1) * 64;
    f32x4 acc[4][4];
#pragma unroll
    for (int i = 0; i < 4; ++i)
#pragma unroll
        for (int j = 0; j < 4; ++j) acc[i][j] = (f32x4){0.f, 0.f, 0.f, 0.f};

    for (int k0 = 0; k0 < CCH; k0 += 32) {
#pragma unroll
        for (int u = 0; u < 2; ++u) {
            int chunk = t + u * 256;
            int row = chunk >> 2, off = (chunk & 3) * 8;
            *(float4*)&As[row * 40 + off] =
                *(const float4*)&Ab[(size_t)(row0 + row) * CCH + k0 + off];
            *(float4*)&Bs[row * 40 + off] =
                *(const float4*)&Bb[(size_t)(col0 + row) * CCH + k0 + off];
        }
        __syncthreads();
        s16x8 af[4], bfr[4];
#pragma unroll
        for (int i = 0; i < 4; ++i)
            af[i] = *(const s16x8*)&As[(wr + i * 16 + lm) * 40 + q * 8];
#pragma unroll
        for (int j = 0; j < 4; ++j)
            bfr[j] = *(const s16x8*)&Bs[(wc + j * 16 + lm) * 40 + q * 8];
#pragma unroll
        for (int i = 0; i < 4; ++i)
#pragma unroll
            for (int j = 0; j < 4; ++j)
                acc[i][j] = __builtin_amdgcn_mfma_f32_16x16x32_bf16(af[i], bfr[j],
                                                                    acc[i][j], 0, 0, 0);
        __syncthreads();
    }
#pragma unroll
    for (int i = 0; i < 4; ++i) {
        int rowb = row0 + wr + i * 16 + q * 4;
#pragma unroll
        for (int r = 0; r < 4; ++r) {
            size_t base = (size_t)(rowb + r) * NM;
#pragma unroll
            for (int j = 0; j < 4; ++j)
                Ob[base + col0 + wc + j * 16 + lm] = f2bf(__expf(acc[i][j][r]));
        }
    }
}

// ---------------------------------------------------------------------------
// k_sumrows: outv[bbase+z, row] = sum over 4096 cols of bf16 matrix row.
// grid (4096, g), block 256.
// ---------------------------------------------------------------------------
__global__ __launch_bounds__(256) void k_sumrows(const short* __restrict__ Mm,
                                                 float* __restrict__ outv, int bbase) {
    int t = threadIdx.x;
    int row = blockIdx.x, z = blockIdx.y;
    const short* src = Mm + (size_t)z * NM * NM + (size_t)row * NM;
    float s = 0.f;
#pragma unroll
    for (int u = 0; u < 2; ++u) {
        int chunk = t + u * 256;
        float4 v = *(const float4*)&src[chunk * 8];
        const short* pp = (const short*)&v;
#pragma unroll
        for (int k = 0; k < 8; ++k) s += bf2f(pp[k]);
    }
#pragma unroll
    for (int off = 32; off; off >>= 1) s += __shfl_down(s, off, 64);
    __shared__ float red[4];
    if ((t & 63) == 0) red[t >> 6] = s;
    __syncthreads();
    if (t == 0) outv[(size_t)(bbase + z) * NM + row] = red[0] + red[1] + red[2] + red[3];
}

// ---------------------------------------------------------------------------
// k_attn: OutT[b,p=row,c=col] = bf16( (sum_k Aop[z,row,k]*B[b,col,k]) / divv[b,row] )
// Aop: group-local (z,4096,4096) bf16 (P or PT). B: (b,c,k) bf16 (or fp32 if use32).
// TM=128, TN=64, BK=32. grid (32, 4, g), block 256.
// ---------------------------------------------------------------------------
__global__ __launch_bounds__(256) void k_attn(const short* __restrict__ Aop,
                                              const short* __restrict__ Bop16,
                                              const float* __restrict__ Bop32,
                                              int use32,
                                              const float* __restrict__ divv,
                                              short* __restrict__ OutT,
                                              int bbase) {
    __shared__ short As[128 * 40];
    __shared__ short Bs[64 * 40];
    int t = threadIdx.x;
    int m0 = blockIdx.x * 128, c0 = blockIdx.y * 64, z = blockIdx.z;
    int b = bbase + z;
    const short* Ab = Aop + (size_t)z * NM * NM;
    const short* B16 = Bop16 + (size_t)b * CCH * HW;
    const float* B32 = Bop32 + (size_t)b * CCH * HW;
    int lm = t & 15, q = (t >> 4) & 3, w = t >> 6;
    int wr = (w >> 1) * 64, wc = (w & 1) * 32;
    f32x4 acc[4][2];
#pragma unroll
    for (int i = 0; i < 4; ++i)
#pragma unroll
        for (int j = 0; j < 2; ++j) acc[i][j] = (f32x4){0.f, 0.f, 0.f, 0.f};

    int brow = t >> 2, boff = (t & 3) * 8;
    for (int k0 = 0; k0 < NM; k0 += 32) {
#pragma unroll
        for (int u = 0; u < 2; ++u) {
            int chunk = t + u * 256;
            int row = chunk >> 2, off = (chunk & 3) * 8;
            *(float4*)&As[row * 40 + off] =
                *(const float4*)&Ab[(size_t)(m0 + row) * NM + k0 + off];
        }
        if (use32) {
            const float* src = &B32[(size_t)(c0 + brow) * HW + k0 + boff];
            float4 v0 = *(const float4*)src;
            float4 v1 = *(const float4*)(src + 4);
            *(short4*)&Bs[brow * 40 + boff] =
                make_short4(f2bf(v0.x), f2bf(v0.y), f2bf(v0.z), f2bf(v0.w));
            *(short4*)&Bs[brow * 40 + boff + 4] =
                make_short4(f2bf(v1.x), f2bf(v1.y), f2bf(v1.z), f2bf(v1.w));
        } else {
            *(float4*)&Bs[brow * 40 + boff] =
                *(const float4*)&B16[(size_t)(c0 + brow) * HW + k0 + boff];
        }
        __syncthreads();
        s16x8 af[4], bfr[2];
#pragma unroll
        for (int i = 0; i < 4; ++i)
            af[i] = *(const s16x8*)&As[(wr + i * 16 + lm) * 40 + q * 8];
#pragma unroll
        for (int j = 0; j < 2; ++j)
            bfr[j] = *(const s16x8*)&Bs[(wc + j * 16 + lm) * 40 + q * 8];
#pragma unroll
        for (int i = 0; i < 4; ++i)
#pragma unroll
            for (int j = 0; j < 2; ++j)
                acc[i][j] = __builtin_amdgcn_mfma_f32_16x16x32_bf16(af[i], bfr[j],
                                                                    acc[i][j], 0, 0, 0);
        __syncthreads();
    }
    short* Ob = OutT + (size_t)b * HW * CCH;
#pragma unroll
    for (int i = 0; i < 4; ++i) {
#pragma unroll
        for (int r = 0; r < 4; ++r) {
            int row = m0 + wr + i * 16 + q * 4 + r;
            float inv = 1.f / divv[(size_t)b * NM + row];
#pragma unroll
            for (int j = 0; j < 2; ++j)
                Ob[(size_t)row * CCH + c0 + wc + j * 16 + lm] = f2bf(acc[i][j][r] * inv);
        }
    }
}

// ---------------------------------------------------------------------------
// k_gate: m[b,p] = sigmoid( sum_c attT[b,p,c]*gw[c] ). grid (B*HW/16, 2)
// ---------------------------------------------------------------------------
__global__ __launch_bounds__(256) void k_gate(const short* __restrict__ eattT,
                                              const short* __restrict__ qattT,
                                              const float* __restrict__ gw,
                                              float* __restrict__ m1,
                                              float* __restrict__ m2) {
    int t = threadIdx.x;
    int which = blockIdx.y;
    const short* att = which ? qattT : eattT;
    float* dst = which ? m2 : m1;
    size_t pg = (size_t)blockIdx.x * 16 + (t >> 4);
    int sub = t & 15;
    const short* rowp = att + pg * CCH + sub * 16;
    float s = 0.f;
#pragma unroll
    for (int k = 0; k < 16; ++k) s = fmaf(bf2f(rowp[k]), gw[sub * 16 + k], s);
    s += __shfl_xor(s, 1, 64);
    s += __shfl_xor(s, 2, 64);
    s += __shfl_xor(s, 4, 64);
    s += __shfl_xor(s, 8, 64);
    if (sub == 0) dst[pg] = 1.f / (1.f + __expf(-s));
}

// ---------------------------------------------------------------------------
// k_final: out[b,o,p] = gate[b,p]*sum_c W16[o,c]*attT[b,p,c]
//                      +           sum_c W16[o,256+c]*inT[b,p,c]
// TM=128(o), TN=64(p), BK=32, two K=256 phases. grid (64, 2, B), block 256.
// ---------------------------------------------------------------------------
__global__ __launch_bounds__(256) void k_final(const short* __restrict__ W16,
                                               const short* __restrict__ attT,
                                               const short* __restrict__ inT,
                                               const float* __restrict__ gate,
                                               float* __restrict__ outp) {
    __shared__ short As[128 * 40];
    __shared__ short Bs[64 * 40];
    int t = threadIdx.x;
    int p0 = blockIdx.x * 64, o0 = blockIdx.y * 128, b = blockIdx.z;
    const short* Tb0 = attT + (size_t)b * HW * CCH;
    const short* Tb1 = inT + (size_t)b * HW * CCH;
    int lm = t & 15, q = (t >> 4) & 3, w = t >> 6;
    int wr = (w >> 1) * 64, wc = (w & 1) * 32;
    f32x4 acc[2][4][2];
#pragma unroll
    for (int ph = 0; ph < 2; ++ph)
#pragma unroll
        for (int i = 0; i < 4; ++i)
#pragma unroll
            for (int j = 0; j < 2; ++j) acc[ph][i][j] = (f32x4){0.f, 0.f, 0.f, 0.f};

    int brow = t >> 2, boff = (t & 3) * 8;
    for (int ph = 0; ph < 2; ++ph) {
        const short* Tb = ph ? Tb1 : Tb0;
        for (int k0 = 0; k0 < CCH; k0 += 32) {
#pragma unroll
            for (int u = 0; u < 2; ++u) {
                int chunk = t + u * 256;
                int row = chunk >> 2, off = (chunk & 3) * 8;
                *(float4*)&As[row * 40 + off] =
                    *(const float4*)&W16[(size_t)(o0 + row) * 512 + ph * 256 + k0 + off];
            }
            *(float4*)&Bs[brow * 40 + boff] =
                *(const float4*)&Tb[(size_t)(p0 + brow) * CCH + k0 + boff];
            __syncthreads();
            s16x8 af[4], bfr[2];
#pragma unroll
            for (int i = 0; i < 4; ++i)
                af[i] = *(const s16x8*)&As[(wr + i * 16 + lm) * 40 + q * 8];
#pragma unroll
            for (int j = 0; j < 2; ++j)
                bfr[j] = *(const s16x8*)&Bs[(wc + j * 16 + lm) * 40 + q * 8];
#pragma unroll
            for (int i = 0; i < 4; ++i)
#pragma unroll
                for (int j = 0; j < 2; ++j)
                    acc[ph][i][j] = __builtin_amdgcn_mfma_f32_16x16x32_bf16(
                        af[i], bfr[j], acc[ph][i][j], 0, 0, 0);
            __syncthreads();
        }
    }
#pragma unroll
    for (int j = 0; j < 2; ++j) {
        int p = p0 + wc + j * 16 + lm;
        float gv = gate[(size_t)b * HW + p];
#pragma unroll
        for (int i = 0; i < 4; ++i)
#pragma unroll
            for (int r = 0; r < 4; ++r) {
                int o = o0 + wr + i * 16 + q * 4 + r;
                outp[((size_t)b * CCH + o) * HW + p] =
                    acc[0][i][j][r] * gv + acc[1][i][j][r];
            }
    }
}

// ---------------------------------------------------------------------------
extern "C" void kernel_launch(void* const* d_in, const int* in_sizes, int n_in,
                              void* d_out, int out_size, void* d_ws, size_t ws_size,
                              hipStream_t stream) {
    (void)in_sizes; (void)n_in; (void)out_size;
    const float* in1 = (const float*)d_in[0];
    const float* in2 = (const float*)d_in[1];
    const float* We  = (const float*)d_in[2];
    const float* gw  = (const float*)d_in[3];
    const float* W1  = (const float*)d_in[4];
    const float* W2  = (const float*)d_in[5];
    float* out = (float*)d_out;
    char* ws = (char*)d_ws;

    const size_t SB  = (size_t)BATCH * CCH * HW * 2;   // bf16 (b,c,hw) bytes: 8 MB
    const size_t WB  = (size_t)CCH * 2 * CCH * 2;      // W16 bytes
    const size_t VB  = (size_t)BATCH * NM * 4;         // per-pixel fp32 vector
    const size_t PS  = (size_t)NM * NM * 2;            // one batch of P, bf16

    size_t off = 0;
    auto alloc = [&](size_t bytes) {
        char* p = ws + off;
        off += (bytes + 255) & ~(size_t)255;
        return p;
    };
    short* W16_1 = (short*)alloc(WB);
    short* W16_2 = (short*)alloc(WB);
    short* Xt16  = (short*)alloc(SB);   // in1^T  (b,p,c)
    short* Qt16  = (short*)alloc(SB);   // in2^T  (b,p,c)
    short* E16n  = (short*)alloc(SB);   // ec     (b,n,d)
    short* eattT = (short*)alloc(SB);   // (b,p,c)
    short* qattT = (short*)alloc(SB);
    float* rowsum = (float*)alloc(VB);
    float* colsum = (float*)alloc(VB);
    float* m1v    = (float*)alloc(VB);
    float* m2v    = (float*)alloc(VB);
    size_t fixed_no_nat = off;          // everything except P/PT and X16/Q16

    // tier selection (deterministic per session; graph-safe)
    int g, useMin = 0;
    size_t natB = 2 * ((SB + 255) & ~(size_t)255);
    if      (ws_size >= fixed_no_nat + 8 * PS + natB) g = 4;
    else if (ws_size >= fixed_no_nat + 4 * PS + natB) g = 2;
    else if (ws_size >= fixed_no_nat + 2 * PS + natB) g = 1;
    else { g = 1; useMin = 1; }

    short* P  = (short*)alloc((size_t)g * PS);
    short* PT = (short*)alloc((size_t)g * PS);
    short* X16 = nullptr;
    short* Q16 = nullptr;
    if (!useMin) {
        X16 = (short*)alloc(SB);
        Q16 = (short*)alloc(SB);
    }

    const int nBCHW = BATCH * CCH * HW;
    const int nW = CCH * 2 * CCH;

    // casts
    if (!useMin) {
        k_cast<<<dim3(nBCHW / 1024), 256, 0, stream>>>(in1, X16, nBCHW);
        k_cast<<<dim3(nBCHW / 1024), 256, 0, stream>>>(in2, Q16, nBCHW);
    }
    k_cast<<<dim3(nW / 1024), 256, 0, stream>>>(W1, W16_1, nW);
    k_cast<<<dim3(nW / 1024), 256, 0, stream>>>(W2, W16_2, nW);
    k_cast_tr<<<dim3(HW / 64, CCH / 64, BATCH), 256, 0, stream>>>(in1, Xt16);
    k_cast_tr<<<dim3(HW / 64, CCH / 64, BATCH), 256, 0, stream>>>(in2, Qt16);
    k_E<<<dim3(16, 64, BATCH), 256, 0, stream>>>(in1, We, E16n);

    for (int bbase = 0; bbase < BATCH; bbase += g) {
        k_gemm_exp<<<dim3(32, 32, g), 256, 0, stream>>>(E16n, Qt16, P, bbase);   // P[n,m]
        k_gemm_exp<<<dim3(32, 32, g), 256, 0, stream>>>(Qt16, E16n, PT, bbase);  // PT[m,n]
        k_sumrows<<<dim3(NM, g), 256, 0, stream>>>(P,  rowsum, bbase);  // sum_m P[n,m]
        k_sumrows<<<dim3(NM, g), 256, 0, stream>>>(PT, colsum, bbase);  // sum_n P[n,m]
        // qattT[m,c] = (sum_n PT[m,n]*X[c,n]) / colsum[m]
        k_attn<<<dim3(32, 4, g), 256, 0, stream>>>(PT, X16, in1, useMin, colsum,
                                                   qattT, bbase);
        // eattT[n,c] = (sum_m P[n,m]*Q[c,m]) / rowsum[n]
        k_attn<<<dim3(32, 4, g), 256, 0, stream>>>(P, Q16, in2, useMin, rowsum,
                                                   eattT, bbase);
    }

    k_gate<<<dim3((BATCH * HW) / 16, 2), 256, 0, stream>>>(eattT, qattT, gw, m1v, m2v);
    k_final<<<dim3(64, 2, BATCH), 256, 0, stream>>>(W16_1, eattT, Xt16, m1v, out);
    k_final<<<dim3(64, 2, BATCH), 256, 0, stream>>>(W16_2, qattT, Qt16, m2v,
                                                    out + (size_t)BATCH * CCH * HW);
}

// Round 3
// 433.224 us; speedup vs baseline: 10.4308x; 1.5857x over previous
//
#include <hip/hip_runtime.h>
#include <cstdint>
#include <cstddef>

#define BATCH 4
#define CCH   256
#define HW    4096
#define NM    4096

typedef __attribute__((ext_vector_type(8))) short s16x8;
typedef __attribute__((ext_vector_type(4))) float f32x4;

__device__ __forceinline__ short f2bf(float f) {
    unsigned u = __float_as_uint(f);
    u += 0x7FFFu + ((u >> 16) & 1u);
    return (short)(u >> 16);
}
__device__ __forceinline__ float bf2f(short s) {
    return __uint_as_float(((unsigned)(unsigned short)s) << 16);
}

// ---------------------------------------------------------------------------
// k_cast: fp32 -> bf16, same layout. n multiple of 4.
// ---------------------------------------------------------------------------
__global__ __launch_bounds__(256) void k_cast(const float* __restrict__ s,
                                              short* __restrict__ d, int n) {
    int i = (blockIdx.x * 256 + threadIdx.x) * 4;
    if (i + 3 < n) {
        float4 v = *(const float4*)&s[i];
        *(short4*)&d[i] = make_short4(f2bf(v.x), f2bf(v.y), f2bf(v.z), f2bf(v.w));
    }
}

// ---------------------------------------------------------------------------
// k_cast_tr: (b,c,p) fp32 -> (b,p,c) bf16.  grid (HW/64, CCH/64, B), block 256
// ---------------------------------------------------------------------------
__global__ __launch_bounds__(256) void k_cast_tr(const float* __restrict__ src,
                                                 short* __restrict__ dst) {
    __shared__ short S[64][72];
    int t = threadIdx.x;
    int p0 = blockIdx.x * 64, c0 = blockIdx.y * 64, b = blockIdx.z;
    const float* sb = src + (size_t)b * CCH * HW;
    short* db = dst + (size_t)b * HW * CCH;
    int tx = t & 15, ty = t >> 4;
#pragma unroll
    for (int i = 0; i < 4; ++i) {
        int c = ty + i * 16;
        float4 v = *(const float4*)&sb[(size_t)(c0 + c) * HW + p0 + tx * 4];
        S[tx * 4 + 0][c] = f2bf(v.x);
        S[tx * 4 + 1][c] = f2bf(v.y);
        S[tx * 4 + 2][c] = f2bf(v.z);
        S[tx * 4 + 3][c] = f2bf(v.w);
    }
    __syncthreads();
#pragma unroll
    for (int i = 0; i < 4; ++i) {
        int p = ty + i * 16;
        short4 v = *(const short4*)&S[p][tx * 4];
        *(short4*)&db[(size_t)(p0 + p) * CCH + c0 + tx * 4] = v;
    }
}

// ---------------------------------------------------------------------------
// k_E: E16n[b,n,d] = bf16( sum_c We[d,c] * in1[b,c,n] ).  grid (16,64,B)
// ---------------------------------------------------------------------------
__global__ __launch_bounds__(256) void k_E(const float* __restrict__ in1,
                                           const float* __restrict__ We,
                                           short* __restrict__ E16n) {
    int t = threadIdx.x;
    int n = blockIdx.x * 256 + t;
    int d0 = blockIdx.y * 4;
    int b = blockIdx.z;
    const float* X = in1 + (size_t)b * CCH * HW;
    float a0 = 0.f, a1 = 0.f, a2 = 0.f, a3 = 0.f;
    for (int c = 0; c < CCH; ++c) {
        float x = X[(size_t)c * HW + n];
        a0 = fmaf(x, We[(d0 + 0) * CCH + c], a0);
        a1 = fmaf(x, We[(d0 + 1) * CCH + c], a1);
        a2 = fmaf(x, We[(d0 + 2) * CCH + c], a2);
        a3 = fmaf(x, We[(d0 + 3) * CCH + c], a3);
    }
    short* Eb = E16n + (size_t)b * HW * CCH;
    *(short4*)&Eb[(size_t)n * CCH + d0] =
        make_short4(f2bf(a0), f2bf(a1), f2bf(a2), f2bf(a3));
}

// ---------------------------------------------------------------------------
// k_gemm_exp: computes 128x128 tile of A[n,m]=sum_d E[n,d]*Qt[m,d], then
// writes P[n,m]=bf16(exp(A)), PT[m,n]=same, plus row/col partial sums.
// grid (32 colblk, 32 rowblk, g), block 256. BK=64.
// ---------------------------------------------------------------------------
__global__ __launch_bounds__(256) void k_gemm_exp(const short* __restrict__ Aop,
                                                  const short* __restrict__ Bop,
                                                  short* __restrict__ P,
                                                  short* __restrict__ PT,
                                                  float* __restrict__ rowpart,
                                                  float* __restrict__ colpart,
                                                  int bbase) {
    __shared__ short As[128 * 72];
    __shared__ short Bs[128 * 72];
    int t = threadIdx.x;
    int bx = blockIdx.x, by = blockIdx.y, z = blockIdx.z;
    int col0 = bx * 128, row0 = by * 128;
    int b = bbase + z;
    const short* Ab = Aop + (size_t)b * HW * CCH;
    const short* Bb = Bop + (size_t)b * HW * CCH;
    short* Pb = P + (size_t)z * NM * NM;
    short* PTb = PT + (size_t)z * NM * NM;
    float* rp = rowpart + (size_t)z * NM * 64;
    float* cp = colpart + (size_t)z * NM * 64;
    int lm = t & 15, q = (t >> 4) & 3, w = t >> 6;
    int wr = (w >> 1) * 64, wc = (w & 1) * 64;
    f32x4 acc[4][4];
#pragma unroll
    for (int i = 0; i < 4; ++i)
#pragma unroll
        for (int j = 0; j < 4; ++j) acc[i][j] = (f32x4){0.f, 0.f, 0.f, 0.f};

    for (int k0 = 0; k0 < CCH; k0 += 64) {
#pragma unroll
        for (int u = 0; u < 4; ++u) {
            int chunk = t + u * 256;
            int row = chunk >> 3, off = (chunk & 7) * 8;
            *(float4*)&As[row * 72 + off] =
                *(const float4*)&Ab[(size_t)(row0 + row) * CCH + k0 + off];
            *(float4*)&Bs[row * 72 + off] =
                *(const float4*)&Bb[(size_t)(col0 + row) * CCH + k0 + off];
        }
        __syncthreads();
#pragma unroll
        for (int kk = 0; kk < 2; ++kk) {
            s16x8 af[4], bfr[4];
#pragma unroll
            for (int i = 0; i < 4; ++i)
                af[i] = *(const s16x8*)&As[(wr + i * 16 + lm) * 72 + kk * 32 + q * 8];
#pragma unroll
            for (int j = 0; j < 4; ++j)
                bfr[j] = *(const s16x8*)&Bs[(wc + j * 16 + lm) * 72 + kk * 32 + q * 8];
#pragma unroll
            for (int i = 0; i < 4; ++i)
#pragma unroll
                for (int j = 0; j < 4; ++j)
                    acc[i][j] = __builtin_amdgcn_mfma_f32_16x16x32_bf16(
                        af[i], bfr[j], acc[i][j], 0, 0, 0);
        }
        __syncthreads();
    }
    // exp in place
#pragma unroll
    for (int i = 0; i < 4; ++i)
#pragma unroll
        for (int j = 0; j < 4; ++j)
#pragma unroll
            for (int r = 0; r < 4; ++r) acc[i][j][r] = __expf(acc[i][j][r]);

    // P[n,m]: scalar bf16 stores (16-lane-contiguous segments)
#pragma unroll
    for (int i = 0; i < 4; ++i)
#pragma unroll
        for (int r = 0; r < 4; ++r) {
            size_t base = (size_t)(row0 + wr + i * 16 + q * 4 + r) * NM;
#pragma unroll
            for (int j = 0; j < 4; ++j)
                Pb[base + col0 + wc + j * 16 + lm] = f2bf(acc[i][j][r]);
        }
    // PT[m,n]: short4 stores (r-contiguous along n)
#pragma unroll
    for (int j = 0; j < 4; ++j) {
        size_t base = (size_t)(col0 + wc + j * 16 + lm) * NM + row0 + wr;
#pragma unroll
        for (int i = 0; i < 4; ++i) {
            short4 v = make_short4(f2bf(acc[i][j][0]), f2bf(acc[i][j][1]),
                                   f2bf(acc[i][j][2]), f2bf(acc[i][j][3]));
            *(short4*)&PTb[base + i * 16 + q * 4] = v;
        }
    }
    // row partial sums (over this block's 64-col half): reduce over j and lm
#pragma unroll
    for (int i = 0; i < 4; ++i)
#pragma unroll
        for (int r = 0; r < 4; ++r) {
            float s = acc[i][0][r] + acc[i][1][r] + acc[i][2][r] + acc[i][3][r];
            s += __shfl_xor(s, 1, 64);
            s += __shfl_xor(s, 2, 64);
            s += __shfl_xor(s, 4, 64);
            s += __shfl_xor(s, 8, 64);
            if (lm == 0)
                rp[(size_t)(row0 + wr + i * 16 + q * 4 + r) * 64 + bx * 2 + (w & 1)] = s;
        }
    // col partial sums (over this block's 64-row half): reduce over i,r and q
#pragma unroll
    for (int j = 0; j < 4; ++j) {
        float s = 0.f;
#pragma unroll
        for (int i = 0; i < 4; ++i)
#pragma unroll
            for (int r = 0; r < 4; ++r) s += acc[i][j][r];
        s += __shfl_xor(s, 16, 64);
        s += __shfl_xor(s, 32, 64);
        if (q == 0)
            cp[(size_t)(col0 + wc + j * 16 + lm) * 64 + by * 2 + (w >> 1)] = s;
    }
}

// ---------------------------------------------------------------------------
// k_redsum: rowsum/colsum[b][r] = sum of 64 partials. grid (g*16, 2), block 256.
// ---------------------------------------------------------------------------
__global__ __launch_bounds__(256) void k_redsum(const float* __restrict__ rowpart,
                                                const float* __restrict__ colpart,
                                                float* __restrict__ rowsum,
                                                float* __restrict__ colsum,
                                                int bbase) {
    int t = threadIdx.x;
    int y = blockIdx.y;
    int gr = blockIdx.x * 256 + t;
    int z = gr >> 12, r = gr & 4095;
    const float* src = (y ? colpart : rowpart) + ((size_t)z * NM + r) * 64;
    float s = 0.f;
#pragma unroll
    for (int u = 0; u < 16; ++u) {
        float4 v = *(const float4*)&src[u * 4];
        s += v.x + v.y + v.z + v.w;
    }
    (y ? colsum : rowsum)[(size_t)(bbase + z) * NM + r] = s;
}

// ---------------------------------------------------------------------------
// k_attn: fp32 partials of OutT[m,c] = sum_k A[m,k]*B[c,k] over a K-chunk.
// which=0: A=P, B=Q16 (eatt).  which=1: A=PT, B=X16 (qatt).
// TM=128, TN=128, BK=64. grid (32, 2, g*2*nks), block 256.
// ---------------------------------------------------------------------------
__global__ __launch_bounds__(256) void k_attn(const short* __restrict__ P,
                                              const short* __restrict__ PT,
                                              const short* __restrict__ Q16,
                                              const short* __restrict__ X16,
                                              float* __restrict__ attpart,
                                              int bbase, int nks, int kchunk) {
    __shared__ short As[128 * 72];
    __shared__ short Bs[128 * 72];
    int t = threadIdx.x;
    int zz = blockIdx.z;
    int ks = zz % nks;
    int rest = zz / nks;
    int which = rest & 1;
    int z = rest >> 1;
    int m0 = blockIdx.x * 128, c0 = blockIdx.y * 128;
    int b = bbase + z;
    const short* Ab = (which ? PT : P) + (size_t)z * NM * NM;
    const short* Bb = (which ? X16 : Q16) + (size_t)b * CCH * HW;
    float* part = attpart + (size_t)((z * 2 + which) * nks + ks) * HW * CCH;
    int lm = t & 15, q = (t >> 4) & 3, w = t >> 6;
    int wr = (w >> 1) * 64, wc = (w & 1) * 64;
    f32x4 acc[4][4];
#pragma unroll
    for (int i = 0; i < 4; ++i)
#pragma unroll
        for (int j = 0; j < 4; ++j) acc[i][j] = (f32x4){0.f, 0.f, 0.f, 0.f};

    int kbase = ks * kchunk;
    for (int k0 = 0; k0 < kchunk; k0 += 64) {
#pragma unroll
        for (int u = 0; u < 4; ++u) {
            int chunk = t + u * 256;
            int row = chunk >> 3, off = (chunk & 7) * 8;
            *(float4*)&As[row * 72 + off] =
                *(const float4*)&Ab[(size_t)(m0 + row) * NM + kbase + k0 + off];
            *(float4*)&Bs[row * 72 + off] =
                *(const float4*)&Bb[(size_t)(c0 + row) * HW + kbase + k0 + off];
        }
        __syncthreads();
#pragma unroll
        for (int kk = 0; kk < 2; ++kk) {
            s16x8 af[4], bfr[4];
#pragma unroll
            for (int i = 0; i < 4; ++i)
                af[i] = *(const s16x8*)&As[(wr + i * 16 + lm) * 72 + kk * 32 + q * 8];
#pragma unroll
            for (int j = 0; j < 4; ++j)
                bfr[j] = *(const s16x8*)&Bs[(wc + j * 16 + lm) * 72 + kk * 32 + q * 8];
#pragma unroll
            for (int i = 0; i < 4; ++i)
#pragma unroll
                for (int j = 0; j < 4; ++j)
                    acc[i][j] = __builtin_amdgcn_mfma_f32_16x16x32_bf16(
                        af[i], bfr[j], acc[i][j], 0, 0, 0);
        }
        __syncthreads();
    }
#pragma unroll
    for (int i = 0; i < 4; ++i)
#pragma unroll
        for (int r = 0; r < 4; ++r) {
            size_t base = (size_t)(m0 + wr + i * 16 + q * 4 + r) * CCH;
#pragma unroll
            for (int j = 0; j < 4; ++j)
                part[base + c0 + wc + j * 16 + lm] = acc[i][j][r];
        }
}

// ---------------------------------------------------------------------------
// k_attn_fin: OutT[b,m,c] = bf16( (sum_ks part) / divv[b,m] ).
// grid (1024, 2, g), block 256 (each thread: 4 consecutive c).
// ---------------------------------------------------------------------------
__global__ __launch_bounds__(256) void k_attn_fin(const float* __restrict__ attpart,
                                                  const float* __restrict__ rowsum,
                                                  const float* __restrict__ colsum,
                                                  short* __restrict__ eattT,
                                                  short* __restrict__ qattT,
                                                  int bbase, int nks) {
    int t = threadIdx.x;
    int which = blockIdx.y;
    int z = blockIdx.z;
    size_t idx4 = ((size_t)blockIdx.x * 256 + t) * 4;
    const float* base = attpart + (size_t)(z * 2 + which) * nks * HW * CCH + idx4;
    float sx = 0.f, sy = 0.f, sz = 0.f, sw = 0.f;
    for (int ks = 0; ks < nks; ++ks) {
        float4 v = *(const float4*)(base + (size_t)ks * HW * CCH);
        sx += v.x; sy += v.y; sz += v.z; sw += v.w;
    }
    int m = (int)(idx4 >> 8);
    const float* dv = which ? colsum : rowsum;
    float inv = 1.f / dv[(size_t)(bbase + z) * NM + m];
    short* dst = (which ? qattT : eattT) + (size_t)(bbase + z) * HW * CCH + idx4;
    *(short4*)dst = make_short4(f2bf(sx * inv), f2bf(sy * inv),
                                f2bf(sz * inv), f2bf(sw * inv));
}

// ---------------------------------------------------------------------------
// k_gate: m[b,p] = sigmoid( sum_c attT[b,p,c]*gw[c] ). grid (B*HW/16, 2)
// ---------------------------------------------------------------------------
__global__ __launch_bounds__(256) void k_gate(const short* __restrict__ eattT,
                                              const short* __restrict__ qattT,
                                              const float* __restrict__ gw,
                                              float* __restrict__ m1,
                                              float* __restrict__ m2) {
    int t = threadIdx.x;
    int which = blockIdx.y;
    const short* att = which ? qattT : eattT;
    float* dst = which ? m2 : m1;
    size_t pg = (size_t)blockIdx.x * 16 + (t >> 4);
    int sub = t & 15;
    const short* rowp = att + pg * CCH + sub * 16;
    float s = 0.f;
#pragma unroll
    for (int k = 0; k < 16; ++k) s = fmaf(bf2f(rowp[k]), gw[sub * 16 + k], s);
    s += __shfl_xor(s, 1, 64);
    s += __shfl_xor(s, 2, 64);
    s += __shfl_xor(s, 4, 64);
    s += __shfl_xor(s, 8, 64);
    if (sub == 0) dst[pg] = 1.f / (1.f + __expf(-s));
}

// ---------------------------------------------------------------------------
// k_final: out[b,o,p] = gate[b,p]*sum_c W16[o,c]*attT[b,p,c]
//                      +           sum_c W16[o,256+c]*inT[b,p,c]
// TM=128(o), TN=64(p), BK=32, two K=256 phases. grid (64, 2, B), block 256.
// ---------------------------------------------------------------------------
__global__ __launch_bounds__(256) void k_final(const short* __restrict__ W16,
                                               const short* __restrict__ attT,
                                               const short* __restrict__ inT,
                                               const float* __restrict__ gate,
                                               float* __restrict__ outp) {
    __shared__ short As[128 * 40];
    __shared__ short Bs[64 * 40];
    int t = threadIdx.x;
    int p0 = blockIdx.x * 64, o0 = blockIdx.y * 128, b = blockIdx.z;
    const short* Tb0 = attT + (size_t)b * HW * CCH;
    const short* Tb1 = inT + (size_t)b * HW * CCH;
    int lm = t & 15, q = (t >> 4) & 3, w = t >> 6;
    int wr = (w >> 1) * 64, wc = (w & 1) * 32;
    f32x4 acc[2][4][2];
#pragma unroll
    for (int ph = 0; ph < 2; ++ph)
#pragma unroll
        for (int i = 0; i < 4; ++i)
#pragma unroll
            for (int j = 0; j < 2; ++j) acc[ph][i][j] = (f32x4){0.f, 0.f, 0.f, 0.f};

    int brow = t >> 2, boff = (t & 3) * 8;
    for (int ph = 0; ph < 2; ++ph) {
        const short* Tb = ph ? Tb1 : Tb0;
        for (int k0 = 0; k0 < CCH; k0 += 32) {
#pragma unroll
            for (int u = 0; u < 2; ++u) {
                int chunk = t + u * 256;
                int row = chunk >> 2, off = (chunk & 3) * 8;
                *(float4*)&As[row * 40 + off] =
                    *(const float4*)&W16[(size_t)(o0 + row) * 512 + ph * 256 + k0 + off];
            }
            *(float4*)&Bs[brow * 40 + boff] =
                *(const float4*)&Tb[(size_t)(p0 + brow) * CCH + k0 + boff];
            __syncthreads();
            s16x8 af[4], bfr[2];
#pragma unroll
            for (int i = 0; i < 4; ++i)
                af[i] = *(const s16x8*)&As[(wr + i * 16 + lm) * 40 + q * 8];
#pragma unroll
            for (int j = 0; j < 2; ++j)
                bfr[j] = *(const s16x8*)&Bs[(wc + j * 16 + lm) * 40 + q * 8];
#pragma unroll
            for (int i = 0; i < 4; ++i)
#pragma unroll
                for (int j = 0; j < 2; ++j)
                    acc[ph][i][j] = __builtin_amdgcn_mfma_f32_16x16x32_bf16(
                        af[i], bfr[j], acc[ph][i][j], 0, 0, 0);
            __syncthreads();
        }
    }
#pragma unroll
    for (int j = 0; j < 2; ++j) {
        int p = p0 + wc + j * 16 + lm;
        float gv = gate[(size_t)b * HW + p];
#pragma unroll
        for (int i = 0; i < 4; ++i)
#pragma unroll
            for (int r = 0; r < 4; ++r) {
                int o = o0 + wr + i * 16 + q * 4 + r;
                outp[((size_t)b * CCH + o) * HW + p] =
                    acc[0][i][j][r] * gv + acc[1][i][j][r];
            }
    }
}

// ---------------------------------------------------------------------------
extern "C" void kernel_launch(void* const* d_in, const int* in_sizes, int n_in,
                              void* d_out, int out_size, void* d_ws, size_t ws_size,
                              hipStream_t stream) {
    (void)in_sizes; (void)n_in; (void)out_size;
    const float* in1 = (const float*)d_in[0];
    const float* in2 = (const float*)d_in[1];
    const float* We  = (const float*)d_in[2];
    const float* gw  = (const float*)d_in[3];
    const float* W1  = (const float*)d_in[4];
    const float* W2  = (const float*)d_in[5];
    float* out = (float*)d_out;
    char* ws = (char*)d_ws;

    const size_t SB = (size_t)BATCH * CCH * HW * 2;    // 8 MB bf16 tensor
    const size_t WB = (size_t)CCH * 2 * CCH * 2;       // 256 KB
    const size_t VB = (size_t)BATCH * NM * 4;          // 64 KB
    const size_t PS = (size_t)NM * NM * 2;             // 32 MB per z
    const size_t RP = (size_t)NM * 64 * 4;             // 1 MB per z
    const size_t AP = (size_t)8 * HW * CCH * 4;        // attpart: 8 slices x 4 MB

    auto pad = [](size_t x) { return (x + 255) & ~(size_t)255; };
    size_t fixed = 2 * pad(WB) + 7 * pad(SB) + 4 * pad(VB) + pad(AP);
    size_t need2 = fixed + 2 * pad(2 * RP) + 2 * pad(2 * PS);
    int g = (ws_size >= need2) ? 2 : 1;
    int nks = (g == 2) ? 2 : 4;          // keep k_attn at 512 blocks either way
    int kchunk = NM / nks;

    size_t off = 0;
    auto alloc = [&](size_t bytes) { char* p = ws + off; off += pad(bytes); return p; };
    short* W16_1 = (short*)alloc(WB);
    short* W16_2 = (short*)alloc(WB);
    short* Xt16  = (short*)alloc(SB);   // in1^T (b,p,c)
    short* Qt16  = (short*)alloc(SB);   // in2^T (b,p,c)
    short* E16n  = (short*)alloc(SB);   // (b,n,d)
    short* eattT = (short*)alloc(SB);
    short* qattT = (short*)alloc(SB);
    short* X16   = (short*)alloc(SB);   // in1 (b,c,p) bf16
    short* Q16   = (short*)alloc(SB);
    float* rowsum = (float*)alloc(VB);
    float* colsum = (float*)alloc(VB);
    float* m1v    = (float*)alloc(VB);
    float* m2v    = (float*)alloc(VB);
    float* attpart = (float*)alloc(AP);
    float* rowpart = (float*)alloc((size_t)g * RP);
    float* colpart = (float*)alloc((size_t)g * RP);
    short* P  = (short*)alloc((size_t)g * PS);
    short* PT = (short*)alloc((size_t)g * PS);

    const int nBCHW = BATCH * CCH * HW;
    const int nW = CCH * 2 * CCH;

    k_cast<<<dim3(nBCHW / 1024), 256, 0, stream>>>(in1, X16, nBCHW);
    k_cast<<<dim3(nBCHW / 1024), 256, 0, stream>>>(in2, Q16, nBCHW);
    k_cast<<<dim3(nW / 1024), 256, 0, stream>>>(W1, W16_1, nW);
    k_cast<<<dim3(nW / 1024), 256, 0, stream>>>(W2, W16_2, nW);
    k_cast_tr<<<dim3(HW / 64, CCH / 64, BATCH), 256, 0, stream>>>(in1, Xt16);
    k_cast_tr<<<dim3(HW / 64, CCH / 64, BATCH), 256, 0, stream>>>(in2, Qt16);
    k_E<<<dim3(16, 64, BATCH), 256, 0, stream>>>(in1, We, E16n);

    for (int bbase = 0; bbase < BATCH; bbase += g) {
        k_gemm_exp<<<dim3(32, 32, g), 256, 0, stream>>>(E16n, Qt16, P, PT,
                                                        rowpart, colpart, bbase);
        k_redsum<<<dim3(g * 16, 2), 256, 0, stream>>>(rowpart, colpart,
                                                      rowsum, colsum, bbase);
        k_attn<<<dim3(32, 2, g * 2 * nks), 256, 0, stream>>>(P, PT, Q16, X16,
                                                             attpart, bbase, nks, kchunk);
        k_attn_fin<<<dim3(1024, 2, g), 256, 0, stream>>>(attpart, rowsum, colsum,
                                                         eattT, qattT, bbase, nks);
    }

    k_gate<<<dim3((BATCH * HW) / 16, 2), 256, 0, stream>>>(eattT, qattT, gw, m1v, m2v);
    k_final<<<dim3(64, 2, BATCH), 256, 0, stream>>>(W16_1, eattT, Xt16, m1v, out);
    k_final<<<dim3(64, 2, BATCH), 256, 0, stream>>>(W16_2, qattT, Qt16, m2v,
                                                    out + (size_t)BATCH * CCH * HW);
}

// Round 4
// 394.655 us; speedup vs baseline: 11.4502x; 1.0977x over previous
//
#include <hip/hip_runtime.h>
#include <cstdint>
#include <cstddef>

#define BATCH 4
#define CCH   256
#define HW    4096
#define NM    4096

typedef __attribute__((ext_vector_type(8))) short s16x8;
typedef __attribute__((ext_vector_type(4))) float f32x4;

__device__ __forceinline__ short f2bf(float f) {
    unsigned u = __float_as_uint(f);
    u += 0x7FFFu + ((u >> 16) & 1u);
    return (short)(u >> 16);
}
__device__ __forceinline__ float bf2f(short s) {
    return __uint_as_float(((unsigned)(unsigned short)s) << 16);
}

// ---------------------------------------------------------------------------
// k_cast: fp32 -> bf16, same layout. n multiple of 4.
// ---------------------------------------------------------------------------
__global__ __launch_bounds__(256) void k_cast(const float* __restrict__ s,
                                              short* __restrict__ d, int n) {
    int i = (blockIdx.x * 256 + threadIdx.x) * 4;
    if (i + 3 < n) {
        float4 v = *(const float4*)&s[i];
        *(short4*)&d[i] = make_short4(f2bf(v.x), f2bf(v.y), f2bf(v.z), f2bf(v.w));
    }
}

// ---------------------------------------------------------------------------
// k_cast_tr: (b,c,p) fp32 -> (b,p,c) bf16.  grid (HW/64, CCH/64, B), block 256
// ---------------------------------------------------------------------------
__global__ __launch_bounds__(256) void k_cast_tr(const float* __restrict__ src,
                                                 short* __restrict__ dst) {
    __shared__ short S[64][72];
    int t = threadIdx.x;
    int p0 = blockIdx.x * 64, c0 = blockIdx.y * 64, b = blockIdx.z;
    const float* sb = src + (size_t)b * CCH * HW;
    short* db = dst + (size_t)b * HW * CCH;
    int tx = t & 15, ty = t >> 4;
#pragma unroll
    for (int i = 0; i < 4; ++i) {
        int c = ty + i * 16;
        float4 v = *(const float4*)&sb[(size_t)(c0 + c) * HW + p0 + tx * 4];
        S[tx * 4 + 0][c] = f2bf(v.x);
        S[tx * 4 + 1][c] = f2bf(v.y);
        S[tx * 4 + 2][c] = f2bf(v.z);
        S[tx * 4 + 3][c] = f2bf(v.w);
    }
    __syncthreads();
#pragma unroll
    for (int i = 0; i < 4; ++i) {
        int p = ty + i * 16;
        short4 v = *(const short4*)&S[p][tx * 4];
        *(short4*)&db[(size_t)(p0 + p) * CCH + c0 + tx * 4] = v;
    }
}

// ---------------------------------------------------------------------------
// k_E_mfma: E16n[b,n,d] = bf16( sum_c Xt16[b,n,c] * We16[d,c] )
// TM=128(n), TN=128(d), BK=64, K=256. grid (2, 32, B), block 256.
// ---------------------------------------------------------------------------
__global__ __launch_bounds__(256) void k_E_mfma(const short* __restrict__ Xt16,
                                                const short* __restrict__ We16,
                                                short* __restrict__ E16n) {
    __shared__ short As[128 * 72];
    __shared__ short Bs[128 * 72];
    int t = threadIdx.x;
    int d0 = blockIdx.x * 128, n0 = blockIdx.y * 128, b = blockIdx.z;
    const short* Xb = Xt16 + (size_t)b * HW * CCH;
    short* Eb = E16n + (size_t)b * HW * CCH;
    int lm = t & 15, q = (t >> 4) & 3, w = t >> 6;
    int wr = (w >> 1) * 64, wc = (w & 1) * 64;
    f32x4 acc[4][4];
#pragma unroll
    for (int i = 0; i < 4; ++i)
#pragma unroll
        for (int j = 0; j < 4; ++j) acc[i][j] = (f32x4){0.f, 0.f, 0.f, 0.f};

    for (int k0 = 0; k0 < CCH; k0 += 64) {
#pragma unroll
        for (int u = 0; u < 4; ++u) {
            int chunk = t + u * 256;
            int row = chunk >> 3, off = (chunk & 7) * 8;
            *(float4*)&As[row * 72 + off] =
                *(const float4*)&Xb[(size_t)(n0 + row) * CCH + k0 + off];
            *(float4*)&Bs[row * 72 + off] =
                *(const float4*)&We16[(size_t)(d0 + row) * CCH + k0 + off];
        }
        __syncthreads();
#pragma unroll
        for (int kk = 0; kk < 2; ++kk) {
            s16x8 af[4], bfr[4];
#pragma unroll
            for (int i = 0; i < 4; ++i)
                af[i] = *(const s16x8*)&As[(wr + i * 16 + lm) * 72 + kk * 32 + q * 8];
#pragma unroll
            for (int j = 0; j < 4; ++j)
                bfr[j] = *(const s16x8*)&Bs[(wc + j * 16 + lm) * 72 + kk * 32 + q * 8];
#pragma unroll
            for (int i = 0; i < 4; ++i)
#pragma unroll
                for (int j = 0; j < 4; ++j)
                    acc[i][j] = __builtin_amdgcn_mfma_f32_16x16x32_bf16(
                        af[i], bfr[j], acc[i][j], 0, 0, 0);
        }
        __syncthreads();
    }
#pragma unroll
    for (int i = 0; i < 4; ++i)
#pragma unroll
        for (int r = 0; r < 4; ++r) {
            size_t base = (size_t)(n0 + wr + i * 16 + q * 4 + r) * CCH;
#pragma unroll
            for (int j = 0; j < 4; ++j)
                Eb[base + d0 + wc + j * 16 + lm] = f2bf(acc[i][j][r]);
        }
}

// ---------------------------------------------------------------------------
// k_fused: flash-style fused score->exp->PV with in-kernel row normalization.
// which=0 (eatt rows n): Arow=E16n, Acol=Qt16, V=Q16.
// which=1 (qatt rows m): Arow=Qt16, Acol=E16n, V=X16.
// Out[row, c] = (sum_col exp(Arow[row,:].Acol[col,:]) * V[c,col]) / rowsum[row]
// 64 rows/block, col-tiles of 128, K=256 in 4 chunks. 512 blocks, 256 thr.
// blockIdx%8 = (b,which) so co-resident blocks on one XCD share operands.
// ---------------------------------------------------------------------------
__global__ __launch_bounds__(256, 2) void k_fused(const short* __restrict__ E16n,
                                                  const short* __restrict__ Qt16,
                                                  const short* __restrict__ Q16,
                                                  const short* __restrict__ X16,
                                                  short* __restrict__ eattT,
                                                  short* __restrict__ qattT) {
    __shared__ short ArS[64 * 72];
    __shared__ short AcS[128 * 72];
    __shared__ short Ps[64 * 136];
    __shared__ float rs[4 * 64];

    int t = threadIdx.x;
    int gid = blockIdx.x;
    int bw = gid & 7;
    int b = bw >> 1, which = bw & 1;
    int r0 = (gid >> 3) * 64;

    const short* Ar = (which ? Qt16 : E16n) + (size_t)b * HW * CCH;
    const short* Ac = (which ? E16n : Qt16) + (size_t)b * HW * CCH;
    const short* V  = (which ? X16  : Q16 ) + (size_t)b * CCH * HW;
    short* Out = (which ? qattT : eattT) + (size_t)b * HW * CCH;

    int lm = t & 15, q = (t >> 4) & 3, w = t >> 6;
    int wq = w * 32;   // this wave's score-column quarter (of 128)
    int cq = w * 64;   // this wave's V-channel quarter (of 256)

    f32x4 oacc[4][4];            // out[row=i*16+q*4+r][c=cq+j*16+lm]
    float rsum[4][4];            // [i][r] partial row sums (this wave's cols)
#pragma unroll
    for (int i = 0; i < 4; ++i) {
#pragma unroll
        for (int j = 0; j < 4; ++j) oacc[i][j] = (f32x4){0.f, 0.f, 0.f, 0.f};
#pragma unroll
        for (int r = 0; r < 4; ++r) rsum[i][r] = 0.f;
    }

    for (int col0 = 0; col0 < NM; col0 += 128) {
        // ---- score phase: S[64][128] = Ar[r0:+64,:256] . Ac[col0:+128,:256]^T
        f32x4 sacc[4][2];
#pragma unroll
        for (int i = 0; i < 4; ++i)
#pragma unroll
            for (int j = 0; j < 2; ++j) sacc[i][j] = (f32x4){0.f, 0.f, 0.f, 0.f};

        for (int kc = 0; kc < CCH; kc += 64) {
#pragma unroll
            for (int u = 0; u < 2; ++u) {        // Ar tile 64x64
                int chunk = t + u * 256;
                int row = chunk >> 3, off = (chunk & 7) * 8;
                *(float4*)&ArS[row * 72 + off] =
                    *(const float4*)&Ar[(size_t)(r0 + row) * CCH + kc + off];
            }
#pragma unroll
            for (int u = 0; u < 4; ++u) {        // Ac tile 128x64
                int chunk = t + u * 256;
                int row = chunk >> 3, off = (chunk & 7) * 8;
                *(float4*)&AcS[row * 72 + off] =
                    *(const float4*)&Ac[(size_t)(col0 + row) * CCH + kc + off];
            }
            __syncthreads();
#pragma unroll
            for (int kk = 0; kk < 2; ++kk) {
                s16x8 af[4], bfr[2];
#pragma unroll
                for (int i = 0; i < 4; ++i)
                    af[i] = *(const s16x8*)&ArS[(i * 16 + lm) * 72 + kk * 32 + q * 8];
#pragma unroll
                for (int j = 0; j < 2; ++j)
                    bfr[j] = *(const s16x8*)&AcS[(wq + j * 16 + lm) * 72 + kk * 32 + q * 8];
#pragma unroll
                for (int i = 0; i < 4; ++i)
#pragma unroll
                    for (int j = 0; j < 2; ++j)
                        sacc[i][j] = __builtin_amdgcn_mfma_f32_16x16x32_bf16(
                            af[i], bfr[j], sacc[i][j], 0, 0, 0);
            }
            __syncthreads();
        }
        // ---- exp + P-tile to LDS + rowsum accumulation
#pragma unroll
        for (int i = 0; i < 4; ++i)
#pragma unroll
            for (int j = 0; j < 2; ++j)
#pragma unroll
                for (int r = 0; r < 4; ++r) {
                    float v = __expf(sacc[i][j][r]);
                    rsum[i][r] += v;
                    Ps[(i * 16 + q * 4 + r) * 136 + wq + j * 16 + lm] = f2bf(v);
                }
        __syncthreads();
        // ---- PV phase: oacc[row][c] += P[row, col0:+128] . V[c, col0:+128]^T
#pragma unroll
        for (int km = 0; km < 4; ++km) {
            s16x8 pf[4], vf[4];
#pragma unroll
            for (int i = 0; i < 4; ++i)
                pf[i] = *(const s16x8*)&Ps[(i * 16 + lm) * 136 + km * 32 + q * 8];
#pragma unroll
            for (int j = 0; j < 4; ++j)
                vf[j] = *(const s16x8*)&V[(size_t)(cq + j * 16 + lm) * HW +
                                          col0 + km * 32 + q * 8];
#pragma unroll
            for (int i = 0; i < 4; ++i)
#pragma unroll
                for (int j = 0; j < 4; ++j)
                    oacc[i][j] = __builtin_amdgcn_mfma_f32_16x16x32_bf16(
                        pf[i], vf[j], oacc[i][j], 0, 0, 0);
        }
        // no trailing sync needed: 8 staging syncs separate these Ps reads
        // from the next iteration's Ps writes.
    }

    // ---- rowsum cross-lane + cross-wave reduction
#pragma unroll
    for (int i = 0; i < 4; ++i)
#pragma unroll
        for (int r = 0; r < 4; ++r) {
            float s = rsum[i][r];
            s += __shfl_xor(s, 1, 64);
            s += __shfl_xor(s, 2, 64);
            s += __shfl_xor(s, 4, 64);
            s += __shfl_xor(s, 8, 64);
            rsum[i][r] = s;
        }
    __syncthreads();   // guard rs vs any earlier use of LDS
    if (lm == 0) {
#pragma unroll
        for (int i = 0; i < 4; ++i)
#pragma unroll
            for (int r = 0; r < 4; ++r)
                rs[w * 64 + i * 16 + q * 4 + r] = rsum[i][r];
    }
    __syncthreads();
#pragma unroll
    for (int i = 0; i < 4; ++i)
#pragma unroll
        for (int r = 0; r < 4; ++r) {
            int row = i * 16 + q * 4 + r;
            float inv = 1.f / (rs[row] + rs[64 + row] + rs[128 + row] + rs[192 + row]);
            size_t base = (size_t)(r0 + row) * CCH;
#pragma unroll
            for (int j = 0; j < 4; ++j)
                Out[base + cq + j * 16 + lm] = f2bf(oacc[i][j][r] * inv);
        }
}

// ---------------------------------------------------------------------------
// k_gate: m[b,p] = sigmoid( sum_c attT[b,p,c]*gw[c] ). grid (B*HW/16, 2)
// ---------------------------------------------------------------------------
__global__ __launch_bounds__(256) void k_gate(const short* __restrict__ eattT,
                                              const short* __restrict__ qattT,
                                              const float* __restrict__ gw,
                                              float* __restrict__ m1,
                                              float* __restrict__ m2) {
    int t = threadIdx.x;
    int which = blockIdx.y;
    const short* att = which ? qattT : eattT;
    float* dst = which ? m2 : m1;
    size_t pg = (size_t)blockIdx.x * 16 + (t >> 4);
    int sub = t & 15;
    const short* rowp = att + pg * CCH + sub * 16;
    float s = 0.f;
#pragma unroll
    for (int k = 0; k < 16; ++k) s = fmaf(bf2f(rowp[k]), gw[sub * 16 + k], s);
    s += __shfl_xor(s, 1, 64);
    s += __shfl_xor(s, 2, 64);
    s += __shfl_xor(s, 4, 64);
    s += __shfl_xor(s, 8, 64);
    if (sub == 0) dst[pg] = 1.f / (1.f + __expf(-s));
}

// ---------------------------------------------------------------------------
// k_final: out[b,o,p] = gate[b,p]*sum_c W16[o,c]*attT[b,p,c]
//                      +           sum_c W16[o,256+c]*inT[b,p,c]
// TM=128(o), TN=64(p), BK=32, two K=256 phases. grid (64, 2, B), block 256.
// ---------------------------------------------------------------------------
__global__ __launch_bounds__(256) void k_final(const short* __restrict__ W16,
                                               const short* __restrict__ attT,
                                               const short* __restrict__ inT,
                                               const float* __restrict__ gate,
                                               float* __restrict__ outp) {
    __shared__ short As[128 * 40];
    __shared__ short Bs[64 * 40];
    int t = threadIdx.x;
    int p0 = blockIdx.x * 64, o0 = blockIdx.y * 128, b = blockIdx.z;
    const short* Tb0 = attT + (size_t)b * HW * CCH;
    const short* Tb1 = inT + (size_t)b * HW * CCH;
    int lm = t & 15, q = (t >> 4) & 3, w = t >> 6;
    int wr = (w >> 1) * 64, wc = (w & 1) * 32;
    f32x4 acc[2][4][2];
#pragma unroll
    for (int ph = 0; ph < 2; ++ph)
#pragma unroll
        for (int i = 0; i < 4; ++i)
#pragma unroll
            for (int j = 0; j < 2; ++j) acc[ph][i][j] = (f32x4){0.f, 0.f, 0.f, 0.f};

    int brow = t >> 2, boff = (t & 3) * 8;
    for (int ph = 0; ph < 2; ++ph) {
        const short* Tb = ph ? Tb1 : Tb0;
        for (int k0 = 0; k0 < CCH; k0 += 32) {
#pragma unroll
            for (int u = 0; u < 2; ++u) {
                int chunk = t + u * 256;
                int row = chunk >> 2, off = (chunk & 3) * 8;
                *(float4*)&As[row * 40 + off] =
                    *(const float4*)&W16[(size_t)(o0 + row) * 512 + ph * 256 + k0 + off];
            }
            *(float4*)&Bs[brow * 40 + boff] =
                *(const float4*)&Tb[(size_t)(p0 + brow) * CCH + k0 + boff];
            __syncthreads();
            s16x8 af[4], bfr[2];
#pragma unroll
            for (int i = 0; i < 4; ++i)
                af[i] = *(const s16x8*)&As[(wr + i * 16 + lm) * 40 + q * 8];
#pragma unroll
            for (int j = 0; j < 2; ++j)
                bfr[j] = *(const s16x8*)&Bs[(wc + j * 16 + lm) * 40 + q * 8];
#pragma unroll
            for (int i = 0; i < 4; ++i)
#pragma unroll
                for (int j = 0; j < 2; ++j)
                    acc[ph][i][j] = __builtin_amdgcn_mfma_f32_16x16x32_bf16(
                        af[i], bfr[j], acc[ph][i][j], 0, 0, 0);
            __syncthreads();
        }
    }
#pragma unroll
    for (int j = 0; j < 2; ++j) {
        int p = p0 + wc + j * 16 + lm;
        float gv = gate[(size_t)b * HW + p];
#pragma unroll
        for (int i = 0; i < 4; ++i)
#pragma unroll
            for (int r = 0; r < 4; ++r) {
                int o = o0 + wr + i * 16 + q * 4 + r;
                outp[((size_t)b * CCH + o) * HW + p] =
                    acc[0][i][j][r] * gv + acc[1][i][j][r];
            }
    }
}

// ---------------------------------------------------------------------------
extern "C" void kernel_launch(void* const* d_in, const int* in_sizes, int n_in,
                              void* d_out, int out_size, void* d_ws, size_t ws_size,
                              hipStream_t stream) {
    (void)in_sizes; (void)n_in; (void)out_size; (void)ws_size;
    const float* in1 = (const float*)d_in[0];
    const float* in2 = (const float*)d_in[1];
    const float* We  = (const float*)d_in[2];
    const float* gw  = (const float*)d_in[3];
    const float* W1  = (const float*)d_in[4];
    const float* W2  = (const float*)d_in[5];
    float* out = (float*)d_out;
    char* ws = (char*)d_ws;

    const size_t SB = (size_t)BATCH * CCH * HW * 2;    // 8 MB bf16 tensor
    const size_t WB = (size_t)CCH * 2 * CCH * 2;       // 256 KB
    const size_t EB = (size_t)CCH * CCH * 2;           // 128 KB (We16)
    const size_t VB = (size_t)BATCH * NM * 4;          // 64 KB

    size_t off = 0;
    auto alloc = [&](size_t bytes) {
        char* p = ws + off;
        off += (bytes + 255) & ~(size_t)255;
        return p;
    };
    short* W16_1 = (short*)alloc(WB);
    short* W16_2 = (short*)alloc(WB);
    short* We16  = (short*)alloc(EB);
    short* Xt16  = (short*)alloc(SB);   // in1^T (b,p,c)
    short* Qt16  = (short*)alloc(SB);   // in2^T (b,p,c)
    short* E16n  = (short*)alloc(SB);   // (b,n,d)
    short* eattT = (short*)alloc(SB);
    short* qattT = (short*)alloc(SB);
    short* X16   = (short*)alloc(SB);   // in1 (b,c,p) bf16
    short* Q16   = (short*)alloc(SB);   // in2 (b,c,p) bf16
    float* m1v   = (float*)alloc(VB);
    float* m2v   = (float*)alloc(VB);

    const int nBCHW = BATCH * CCH * HW;
    const int nW = CCH * 2 * CCH;
    const int nWe = CCH * CCH;

    k_cast<<<dim3(nBCHW / 1024), 256, 0, stream>>>(in1, X16, nBCHW);
    k_cast<<<dim3(nBCHW / 1024), 256, 0, stream>>>(in2, Q16, nBCHW);
    k_cast<<<dim3(nW / 1024), 256, 0, stream>>>(W1, W16_1, nW);
    k_cast<<<dim3(nW / 1024), 256, 0, stream>>>(W2, W16_2, nW);
    k_cast<<<dim3(nWe / 1024), 256, 0, stream>>>(We, We16, nWe);
    k_cast_tr<<<dim3(HW / 64, CCH / 64, BATCH), 256, 0, stream>>>(in1, Xt16);
    k_cast_tr<<<dim3(HW / 64, CCH / 64, BATCH), 256, 0, stream>>>(in2, Qt16);

    k_E_mfma<<<dim3(2, 32, BATCH), 256, 0, stream>>>(Xt16, We16, E16n);

    k_fused<<<dim3(512), 256, 0, stream>>>(E16n, Qt16, Q16, X16, eattT, qattT);

    k_gate<<<dim3((BATCH * HW) / 16, 2), 256, 0, stream>>>(eattT, qattT, gw, m1v, m2v);
    k_final<<<dim3(64, 2, BATCH), 256, 0, stream>>>(W16_1, eattT, Xt16, m1v, out);
    k_final<<<dim3(64, 2, BATCH), 256, 0, stream>>>(W16_2, qattT, Qt16, m2v,
                                                    out + (size_t)BATCH * CCH * HW);
}